// Round 11
// baseline (4603.302 us; speedup 1.0000x reference)
//
#include <hip/hip_runtime.h>
#include <math.h>

#define NUMPIX 256
#define NUMBIN 367
#define NUMTHETA 360
#define NS 4
#define NT 367
#define NPIX2 (NUMPIX * NUMPIX)          // 65536
#define NRAYS_ALL (NUMTHETA * NUMBIN)    // 132120
#define NANG_SUB (NUMTHETA / NS)         // 90
#define NRAYS_SUB (NANG_SUB * NUMBIN)    // 33030

#define CDET 183.0f
#define CPIX 127.5f
#define TOFF 183.0f                      // (NT-1)/2
#define DEN_EPS 1e-6f
#define EPS_F 2.2204460492503131e-16f    // float64 eps
#define RES2_THRESH 1e-4f                // (0.01)^2
#define INV_DINV (1.0f / 90.0f)          // backproject(ones) == 90 exactly

// quad-interleaved image: element (r,c) = float2(img[r][c], img[r+1][c])
// rows r in [-1,256] stored at +1 (258 rows), cols c in [-1,258] at +1
// NOTE: the sampling clamp to [-1,256] is the TAIL MASK for up-to-63
// overshoot lanes of the rounded-up chunk loop. Do NOT remove (round-8 bug).
#define QW 260                           // float2 stride
#define QROWS 258
#define QN2 (QW * QROWS)                 // 67080 float2
#define QNF (QN2 * 2)                    // 134160 floats

#define NTHREADS 256

typedef float f4q __attribute__((ext_vector_type(4), aligned(8)));
typedef float f2u __attribute__((ext_vector_type(2), aligned(4)));

// ---- workspace layout (in floats) ----
#define OFF_COS   0
#define OFF_SIN   (OFF_COS + NUMTHETA)           // 360
#define OFF_MINV  (OFF_SIN + NUMTHETA)           // 720
#define OFF_FK    (OFF_MINV + NRAYS_ALL)         // 132840
#define OFF_Q     (OFF_FK + NPIX2)               // 198376 (even -> float2 ok)
#define OFF_QT    (OFF_Q + QNF)                  // 332536
#define OFF_DIFF  (OFF_QT + QNF)                 // 466696 (also residual partials)
#define OFF_BAR   (OFF_DIFF + NRAYS_SUB)         // 499726 (barrier ints)
#define BAR_INTS  1056                           // 32 groups * 32 stride + root

// generic t-interval clip: keep c0 + rate*tt within (bLo, bHi)
__device__ __forceinline__ void clip_axis2(float c0, float rate,
                                           float bLo, float bHi,
                                           float& lo, float& hi) {
    if (fabsf(rate) > 1e-6f) {
        float inv = 1.0f / rate;
        float a = (bLo - c0) * inv;
        float b = (bHi - c0) * inv;
        lo = fmaxf(lo, fminf(a, b));
        hi = fminf(hi, fmaxf(a, b));
    } else if (c0 <= bLo || c0 >= bHi) {
        lo = 1e9f; hi = -1e9f;
    }
}

__device__ __forceinline__ int ray_chunks(float x0, float y0, float ca, float sa,
                                          int& itlo) {
    float lo = -1e9f, hi = 1e9f;
    clip_axis2(x0, -sa, -2.0f, 257.0f, lo, hi);
    clip_axis2(y0,  ca, -2.0f, 257.0f, lo, hi);
    if (hi < lo) { itlo = 0; return 0; }
    int a = (int)floorf(lo + TOFF) - 1; if (a < 0) a = 0;
    int b = (int)ceilf(hi + TOFF) + 1;  if (b > NT - 1) b = NT - 1;
    itlo = a;
    if (b < a) return 0;
    return (b - a + 64) >> 6;
}

// forward projection of one ray; wave-reduced sum valid on lane 0
__device__ __forceinline__ float fp_ray(int angle, int bin, int lane,
                                        const float* __restrict__ Qn,
                                        const float* __restrict__ Qt,
                                        const float* __restrict__ cosA,
                                        const float* __restrict__ sinA) {
    float ca = cosA[angle], sa = sinA[angle];
    float s = (float)bin - CDET;
    float x0 = fmaf(s, ca, CPIX);             // x(tt) = x0 - tt*sa
    float y0 = fmaf(s, sa, CPIX);             // y(tt) = y0 + tt*ca
    int itlo, nc = ray_chunks(x0, y0, ca, sa, itlo);

    bool useT = fabsf(ca) > fabsf(sa);        // wave-uniform
    const float* img = (useT ? Qt : Qn) + (QW + 1) * 2;  // element (0,0)
    float u0 = useT ? y0 : x0, du = useT ? ca : -sa;   // fast (contiguous)
    float v0 = useT ? x0 : y0, dv = useT ? -sa : ca;   // slow (strided)

    float tt0 = (float)(itlo + lane) - TOFF;
    float u = fmaf(tt0, du, u0);
    float v = fmaf(tt0, dv, v0);
    const float du64 = du * 64.0f, dv64 = dv * 64.0f;

    float acc = 0.0f;
    for (int ic = 0; ic < nc; ic++) {
        float uc = fminf(fmaxf(u, -1.0f), 256.0f);   // tail mask + guard
        float vc = fminf(fmaxf(v, -1.0f), 256.0f);
        float fu = floorf(uc), fv = floorf(vc);
        float wu = uc - fu, wv = vc - fv;
        int idx = (int)fmaf(fv, (float)QW, fu);      // exact int fp32 index
        const float* p = img + idx * 2;
        f4q q = *(const f4q*)p;   // (v00, v10, v01, v11) in one 16B load
        float top = fmaf(wu, q.z - q.x, q.x);
        float bot = fmaf(wu, q.w - q.y, q.y);
        acc += fmaf(wv, bot - top, top);
        u += du64; v += dv64;
    }
    #pragma unroll
    for (int off = 32; off; off >>= 1) acc += __shfl_down(acc, off);
    return acc;
}

// monotonic two-level grid barrier. bar[g*32] = group counters (g<32),
// bar[1024] = root. k = 1,2,3,... strictly increasing per call site.
__device__ __forceinline__ void grid_barrier(int* bar, int k, int nb) {
    __threadfence();              // release: prior writes visible device-wide
    __syncthreads();
    if (threadIdx.x == 0) {
        int g = blockIdx.x & 31;
        int nb_g = (nb - g + 31) >> 5;          // blocks with id%32==g
        int ng = (nb < 32) ? nb : 32;
        int old = atomicAdd(&bar[g * 32], 1);   // device scope by default
        if (old == nb_g * k - 1) atomicAdd(&bar[1024], 1);
        long long t0 = clock64();
        while (__hip_atomic_load(&bar[1024], __ATOMIC_ACQUIRE,
                                 __HIP_MEMORY_SCOPE_AGENT) < ng * k) {
            __builtin_amdgcn_s_sleep(8);
            if (clock64() - t0 > 2000000000LL) break;   // deadlock bailout
        }
    }
    __syncthreads();
    __threadfence();              // acquire: invalidate stale cache lines
}

// ---------------- init: trig + quad images + fk/fcur + barrier zero ------
__global__ void init_kernel(float* __restrict__ cosA, float* __restrict__ sinA,
                            float* __restrict__ Qf, float* __restrict__ QTf,
                            float* __restrict__ fk, float* __restrict__ fcur,
                            const float* __restrict__ f0, int* __restrict__ bar) {
    int idx = blockIdx.x * blockDim.x + threadIdx.x;
    if (idx < NUMTHETA) {
        float th = (float)((double)idx * 0.017453292519943295);
        cosA[idx] = (float)cos((double)th);
        sinA[idx] = (float)sin((double)th);
    }
    if (idx < BAR_INTS) bar[idx] = 0;
    if (idx < NPIX2) {
        float v = f0[idx];
        fk[idx] = v;
        fcur[idx] = v;
    }
    if (idx < QN2) {
        int qr = idx / QW, qc = idx - qr * QW;
        int r = qr - 1, c = qc - 1;
        bool cv = ((unsigned)c < 256u);
        bool rv0 = ((unsigned)r < 256u), rv1 = ((unsigned)(r + 1) < 256u);
        float a = (cv && rv0) ? f0[r * NUMPIX + c] : 0.0f;
        float b = (cv && rv1) ? f0[(r + 1) * NUMPIX + c] : 0.0f;
        Qf[idx * 2] = a;  Qf[idx * 2 + 1] = b;
        float ta = (cv && rv0) ? f0[c * NUMPIX + r] : 0.0f;
        float tb = (cv && rv1) ? f0[c * NUMPIX + (r + 1)] : 0.0f;
        QTf[idx * 2] = ta;  QTf[idx * 2 + 1] = tb;
    }
}

// ---------------- Minv: analytic interior count + exact edge samples -----
__global__ __launch_bounds__(256)
void minv_kernel(float* __restrict__ minv,
                 const float* __restrict__ cosA,
                 const float* __restrict__ sinA) {
    const int wid = threadIdx.x >> 6, lane = threadIdx.x & 63;
    int ray = blockIdx.x * 4 + wid;               // grid 33030 -> 132120 exact
    int angle = ray / NUMBIN;
    int bin = ray - angle * NUMBIN;
    float ca = cosA[angle], sa = sinA[angle];
    float s = (float)bin - CDET;
    float x0 = fmaf(s, ca, CPIX);
    float y0 = fmaf(s, sa, CPIX);
    float acc = 0.0f;
    int count = 0;
    float lo = -1e9f, hi = 1e9f;
    clip_axis2(x0, -sa, -2.0f, 257.0f, lo, hi);
    clip_axis2(y0,  ca, -2.0f, 257.0f, lo, hi);
    int e1a = 0, e1b = -1, e2a = 0, e2b = -1;
    if (hi >= lo) {
        int itA = (int)floorf(lo + TOFF) - 1; if (itA < 0) itA = 0;
        int itB = (int)ceilf(hi + TOFF) + 1;  if (itB > NT - 1) itB = NT - 1;
        if (itB >= itA) {
            float ilo = -1e9f, ihi = 1e9f;
            clip_axis2(x0, -sa, 0.05f, 254.95f, ilo, ihi);
            clip_axis2(y0,  ca, 0.05f, 254.95f, ilo, ihi);
            int jA = 1, jB = 0;
            if (ihi >= ilo) {
                jA = (int)ceilf(ilo + TOFF) + 1;
                jB = (int)floorf(ihi + TOFF) - 1;
                if (jA < itA) jA = itA;
                if (jB > itB) jB = itB;
            }
            if (jB >= jA) {
                count = jB - jA + 1;
                e1a = itA; e1b = jA - 1;
                e2a = jB + 1; e2b = itB;
            } else {
                e1a = itA; e1b = itB;
            }
        }
    }
    #pragma unroll 1
    for (int base = e1a; base <= e1b; base += 64) {
        int t = base + lane;
        float tt = (float)t - TOFF;
        float x = fmaf(-tt, sa, x0);
        float y = fmaf(tt, ca, y0);
        float fx = floorf(x), fy = floorf(y);
        float wx = x - fx, wy = y - fy;
        int c0 = (int)fx, r0 = (int)fy;
        float ux = (((unsigned)c0 < 256u) ? (1.0f - wx) : 0.0f) +
                   (((unsigned)(c0 + 1) < 256u) ? wx : 0.0f);
        float uy = (((unsigned)r0 < 256u) ? (1.0f - wy) : 0.0f) +
                   (((unsigned)(r0 + 1) < 256u) ? wy : 0.0f);
        if (t <= e1b) acc += ux * uy;
    }
    #pragma unroll 1
    for (int base = e2a; base <= e2b; base += 64) {
        int t = base + lane;
        float tt = (float)t - TOFF;
        float x = fmaf(-tt, sa, x0);
        float y = fmaf(tt, ca, y0);
        float fx = floorf(x), fy = floorf(y);
        float wx = x - fx, wy = y - fy;
        int c0 = (int)fx, r0 = (int)fy;
        float ux = (((unsigned)c0 < 256u) ? (1.0f - wx) : 0.0f) +
                   (((unsigned)(c0 + 1) < 256u) ? wx : 0.0f);
        float uy = (((unsigned)r0 < 256u) ? (1.0f - wy) : 0.0f) +
                   (((unsigned)(r0 + 1) < 256u) ? wy : 0.0f);
        if (t <= e2b) acc += ux * uy;
    }
    #pragma unroll
    for (int off = 32; off; off >>= 1) acc += __shfl_down(acc, off);
    if (lane == 0) minv[ray] = fmaxf(acc + (float)count, DEN_EPS);
}

// ---------------- persistent mega kernel: both SART iterations -----------
__global__ __launch_bounds__(NTHREADS)
void sart_mega(const float* __restrict__ sino, float* __restrict__ fcur,
               const float* __restrict__ cosA, const float* __restrict__ sinA,
               const float* __restrict__ minv, float* __restrict__ fk,
               float* __restrict__ Qf, float* __restrict__ QTf,
               float* __restrict__ diff, int* __restrict__ bar) {
    const int tid = threadIdx.x;
    const int lane = tid & 63;
    const int wid = tid >> 6;
    const int nb = gridDim.x;
    const int NW = nb << 2;                       // total waves
    const int gwave = (blockIdx.x << 2) + wid;
    __shared__ float part[4][64];
    int bk = 0;

    for (int iter = 0; iter < 2; iter++) {
        for (int j = 0; j < NS; j++) {
            // ---- FP subset j -> diffs
            for (int ray = gwave; ray < NRAYS_SUB; ray += NW) {
                int ai = ray / NUMBIN;
                int bin = ray - ai * NUMBIN;
                int angle = j + ai * NS;
                float acc = fp_ray(angle, bin, lane, Qf, QTf, cosA, sinA);
                if (lane == 0)
                    diff[ray] = (sino[angle * NUMBIN + bin] - acc) /
                                minv[angle * NUMBIN + bin];
            }
            grid_barrier(bar, ++bk, nb);

            // ---- BP + SART update (64 pixels per block-iteration)
            for (int pb = blockIdx.x; pb < NPIX2 / 64; pb += nb) {
                int p = pb * 64 + lane;
                int px = p & (NUMPIX - 1), py = p >> 8;
                float X = (float)px - CPIX, Y = (float)py - CPIX;
                float acc = 0.0f;
                for (int i = wid; i < NANG_SUB; i += 4) {
                    int angle = j + NS * i;
                    float ca = cosA[angle], sa = sinA[angle];
                    float sd = fmaf(X, ca, fmaf(Y, sa, CDET)); // [2.7,363.3]
                    float fl = floorf(sd);
                    float w = sd - fl;
                    int i0 = (int)fl;
                    f2u gv = *(const f2u*)(diff + i * NUMBIN + i0);
                    acc += fmaf(w, gv.y - gv.x, gv.x);
                }
                part[wid][lane] = acc;
                __syncthreads();
                if (wid == 0) {
                    float sm = part[0][lane] + part[1][lane] +
                               part[2][lane] + part[3][lane];
                    float bp = (fabsf(sm) > 1000.0f) ? 0.0f : sm;
                    float v = fk[p] + bp * INV_DINV;
                    if (j == NS - 1) v = fmaxf(v, EPS_F);
                    fk[p] = v;
                    Qf[((py + 1) * QW + (px + 1)) * 2]      = v;
                    Qf[(py * QW + (px + 1)) * 2 + 1]        = v;
                    QTf[((px + 1) * QW + (py + 1)) * 2]     = v;
                    QTf[(px * QW + (py + 1)) * 2 + 1]       = v;
                }
                __syncthreads();
            }
            grid_barrier(bar, ++bk, nb);
        }

        // ---- residual: per-wave partials into diff[0..NW-1]
        {
            float wacc = 0.0f;
            for (int ray = gwave; ray < NRAYS_ALL; ray += NW) {
                int angle = ray / NUMBIN;
                int bin = ray - angle * NUMBIN;
                float acc = fp_ray(angle, bin, lane, Qf, QTf, cosA, sinA);
                if (lane == 0) {
                    float d = acc - sino[ray];
                    wacc += d * d;
                }
            }
            if (lane == 0) diff[gwave] = wacc;
        }
        grid_barrier(bar, ++bk, nb);

        // ---- select: every block reduces NW partials + commits its pixels
        {
            float a = 0.0f;
            for (int idx = tid; idx < NW; idx += NTHREADS) a += diff[idx];
            #pragma unroll
            for (int off = 32; off; off >>= 1) a += __shfl_down(a, off);
            if (lane == 0) part[wid][0] = a;
            __syncthreads();
            float tot = part[0][0] + part[1][0] + part[2][0] + part[3][0];
            bool upd = (tot > RES2_THRESH);   // res = sqrt(res2) > 0.01
            for (int p = blockIdx.x * NTHREADS + tid; p < NPIX2;
                 p += nb * NTHREADS) {
                int px = p & (NUMPIX - 1), py = p >> 8;
                float v = upd ? fk[p] : fcur[p];
                fcur[p] = v;
                fk[p] = v;
                Qf[((py + 1) * QW + (px + 1)) * 2]      = v;
                Qf[(py * QW + (px + 1)) * 2 + 1]        = v;
                QTf[((px + 1) * QW + (py + 1)) * 2]     = v;
                QTf[(px * QW + (py + 1)) * 2 + 1]       = v;
            }
            __syncthreads();
        }
        grid_barrier(bar, ++bk, nb);
    }
}

extern "C" void kernel_launch(void* const* d_in, const int* in_sizes, int n_in,
                              void* d_out, int out_size, void* d_ws, size_t ws_size,
                              hipStream_t stream) {
    const float* f0 = (const float*)d_in[0];     // [256,256]
    const float* sino = (const float*)d_in[1];   // [360,367]
    float* fcur = (float*)d_out;                 // [256,256] output "f"
    float* ws = (float*)d_ws;

    float* cosA = ws + OFF_COS;
    float* sinA = ws + OFF_SIN;
    float* minv = ws + OFF_MINV;   // [360,367] indexed by global angle
    float* fk   = ws + OFF_FK;     // [256,256]
    float* Qf   = ws + OFF_Q;      // quad image (normal)
    float* QTf  = ws + OFF_QT;     // quad image (transposed)
    float* diff = ws + OFF_DIFF;   // [90,367]; also residual partials
    int*   bar  = (int*)(ws + OFF_BAR);

    // co-residency-safe persistent grid (host-only queries; graph-safe)
    int dev = 0;
    (void)hipGetDevice(&dev);
    int nCU = 256;
    (void)hipDeviceGetAttribute(&nCU, hipDeviceAttributeMultiprocessorCount, dev);
    int maxB = 0;
    (void)hipOccupancyMaxActiveBlocksPerMultiprocessor(&maxB, sart_mega,
                                                       NTHREADS, 0);
    if (maxB < 1) maxB = 1;
    long long nbl = (long long)maxB * nCU;
    int nb = (nbl > 2048) ? 2048 : (int)nbl;
    if (nb < 32) nb = 32;

    init_kernel<<<(QN2 + 255) / 256, 256, 0, stream>>>(
        cosA, sinA, Qf, QTf, fk, fcur, f0, bar);

    minv_kernel<<<NRAYS_ALL / 4, 256, 0, stream>>>(minv, cosA, sinA);

    sart_mega<<<nb, NTHREADS, 0, stream>>>(
        sino, fcur, cosA, sinA, minv, fk, Qf, QTf, diff, bar);
}

// Round 12
// 362.758 us; speedup vs baseline: 12.6897x; 12.6897x over previous
//
#include <hip/hip_runtime.h>
#include <math.h>

#define NUMPIX 256
#define NUMBIN 367
#define NUMTHETA 360
#define NS 4
#define NT 367
#define NPIX2 (NUMPIX * NUMPIX)          // 65536
#define NRAYS_ALL (NUMTHETA * NUMBIN)    // 132120
#define NANG_SUB (NUMTHETA / NS)         // 90
#define NRAYS_SUB (NANG_SUB * NUMBIN)    // 33030

#define CDET 183.0f
#define CPIX 127.5f
#define TOFF 183.0f                      // (NT-1)/2
#define DEN_EPS 1e-6f
#define EPS_F 2.2204460492503131e-16f    // float64 eps
#define RES2_THRESH 1e-4f                // (0.01)^2
#define INV_DINV (1.0f / 90.0f)          // backproject(ones) == 90 exactly

// quad-interleaved image: element (r,c) = float2(img[r][c], img[r+1][c])
// rows r in [-1,256] stored at +1 (258 rows), cols c in [-1,258] at +1
// NOTE: sampling clamps coords to [-1,256]; the clamp is the TAIL MASK for
// the up-to-63 overshoot lanes of the rounded-up chunk loop (clamped samples
// read a zero pad cell with weight 0 on the interior side -> contribute 0).
// Do NOT remove it (round-8 failure). Grid-wide-sync fusion abandoned
// (rounds 10/11: co-residency not reliable on this part).
#define QW 260                           // float2 stride
#define QROWS 258
#define QN2 (QW * QROWS)                 // 67080 float2
#define QNF (QN2 * 2)                    // 134160 floats

#define RES_BLOCKS 4096                  // MODE-2 grid (grid-stride)

typedef float f4q __attribute__((ext_vector_type(4), aligned(8)));
typedef float f2u __attribute__((ext_vector_type(2), aligned(4)));

// ---- workspace layout (in floats) ----
#define OFF_COS   0
#define OFF_SIN   (OFF_COS + NUMTHETA)           // 360
#define OFF_MINV  (OFF_SIN + NUMTHETA)           // 720
#define OFF_FK    (OFF_MINV + NRAYS_ALL)         // 132840
#define OFF_Q     (OFF_FK + NPIX2)               // 198376 (even -> float2 ok)
#define OFF_QT    (OFF_Q + QNF)                  // 332536
#define OFF_DIFF  (OFF_QT + QNF)                 // 466696 (also residual partials)

// generic t-interval clip: keep c0 + rate*tt within (bLo, bHi)
__device__ __forceinline__ void clip_axis2(float c0, float rate,
                                           float bLo, float bHi,
                                           float& lo, float& hi) {
    if (fabsf(rate) > 1e-6f) {
        float inv = 1.0f / rate;
        float a = (bLo - c0) * inv;
        float b = (bHi - c0) * inv;
        lo = fmaxf(lo, fminf(a, b));
        hi = fminf(hi, fmaxf(a, b));
    } else if (c0 <= bLo || c0 >= bHi) {
        lo = 1e9f; hi = -1e9f;
    }
}

__device__ __forceinline__ int ray_chunks(float x0, float y0, float ca, float sa,
                                          int& itlo) {
    float lo = -1e9f, hi = 1e9f;
    clip_axis2(x0, -sa, -2.0f, 257.0f, lo, hi);
    clip_axis2(y0,  ca, -2.0f, 257.0f, lo, hi);
    if (hi < lo) { itlo = 0; return 0; }
    int a = (int)floorf(lo + TOFF) - 1; if (a < 0) a = 0;
    int b = (int)ceilf(hi + TOFF) + 1;  if (b > NT - 1) b = NT - 1;
    itlo = a;
    if (b < a) return 0;
    return (b - a + 64) >> 6;
}

// ---------------- init: trig + fk/fcur + quad images ----------------
__global__ void init_kernel(float* __restrict__ cosA, float* __restrict__ sinA,
                            float* __restrict__ Qf, float* __restrict__ QTf,
                            float* __restrict__ fk, float* __restrict__ fcur,
                            const float* __restrict__ f0) {
    int idx = blockIdx.x * blockDim.x + threadIdx.x;
    if (idx < NUMTHETA) {
        float th = (float)((double)idx * 0.017453292519943295);
        cosA[idx] = (float)cos((double)th);
        sinA[idx] = (float)sin((double)th);
    }
    if (idx < NPIX2) {
        float v = f0[idx];
        fk[idx] = v;
        fcur[idx] = v;
    }
    if (idx < QN2) {
        int qr = idx / QW, qc = idx - qr * QW;
        int r = qr - 1, c = qc - 1;                 // r in [-1,256], c in [-1,258]
        bool cv = ((unsigned)c < 256u);
        bool rv0 = ((unsigned)r < 256u), rv1 = ((unsigned)(r + 1) < 256u);
        float a = (cv && rv0) ? f0[r * NUMPIX + c] : 0.0f;
        float b = (cv && rv1) ? f0[(r + 1) * NUMPIX + c] : 0.0f;
        Qf[idx * 2] = a;  Qf[idx * 2 + 1] = b;
        // transposed image: imgT(r,c) = f0[c][r]
        float ta = (cv && rv0) ? f0[c * NUMPIX + r] : 0.0f;
        float tb = (cv && rv1) ? f0[c * NUMPIX + (r + 1)] : 0.0f;
        QTf[idx * 2] = ta;  QTf[idx * 2 + 1] = tb;
    }
}

// ---------------- Minv: analytic interior count + exact edge samples -----
// 16 lanes per ray (4 rays/wave): edge intervals avg ~25 samples, so 64-lane
// chunks wasted ~70% of lanes; 16-lane granularity recovers ~2.5x.
__global__ __launch_bounds__(256)
void minv_kernel(float* __restrict__ minv,
                 const float* __restrict__ cosA,
                 const float* __restrict__ sinA) {
    const int lane = threadIdx.x & 63;
    const int wid = threadIdx.x >> 6;
    const int sub = lane >> 4, slane = lane & 15;
    int ray = blockIdx.x * 16 + wid * 4 + sub;
    if (ray >= NRAYS_ALL) return;            // whole 16-lane group exits
    int angle = ray / NUMBIN;
    int bin = ray - angle * NUMBIN;
    float ca = cosA[angle], sa = sinA[angle];
    float s = (float)bin - CDET;
    float x0 = fmaf(s, ca, CPIX);                 // x(tt) = x0 - tt*sa
    float y0 = fmaf(s, sa, CPIX);                 // y(tt) = y0 + tt*ca
    float acc = 0.0f;
    int count = 0;
    float lo = -1e9f, hi = 1e9f;
    clip_axis2(x0, -sa, -2.0f, 257.0f, lo, hi);
    clip_axis2(y0,  ca, -2.0f, 257.0f, lo, hi);
    int e1a = 0, e1b = -1, e2a = 0, e2b = -1;
    if (hi >= lo) {
        int itA = (int)floorf(lo + TOFF) - 1; if (itA < 0) itA = 0;
        int itB = (int)ceilf(hi + TOFF) + 1;  if (itB > NT - 1) itB = NT - 1;
        if (itB >= itA) {
            // strict interior: both coords in (0.05, 254.95) -> weight exactly 1
            float ilo = -1e9f, ihi = 1e9f;
            clip_axis2(x0, -sa, 0.05f, 254.95f, ilo, ihi);
            clip_axis2(y0,  ca, 0.05f, 254.95f, ilo, ihi);
            int jA = 1, jB = 0;
            if (ihi >= ilo) {
                jA = (int)ceilf(ilo + TOFF) + 1;
                jB = (int)floorf(ihi + TOFF) - 1;
                if (jA < itA) jA = itA;
                if (jB > itB) jB = itB;
            }
            if (jB >= jA) {
                count = jB - jA + 1;
                e1a = itA; e1b = jA - 1;
                e2a = jB + 1; e2b = itB;
            } else {
                e1a = itA; e1b = itB;       // no interior: one full edge loop
            }
        }
    }
    #pragma unroll 1
    for (int base = e1a; base <= e1b; base += 16) {
        int t = base + slane;
        float tt = (float)t - TOFF;
        float x = fmaf(-tt, sa, x0);
        float y = fmaf(tt, ca, y0);
        float fx = floorf(x), fy = floorf(y);
        float wx = x - fx, wy = y - fy;
        int c0 = (int)fx, r0 = (int)fy;
        float ux = (((unsigned)c0 < 256u) ? (1.0f - wx) : 0.0f) +
                   (((unsigned)(c0 + 1) < 256u) ? wx : 0.0f);
        float uy = (((unsigned)r0 < 256u) ? (1.0f - wy) : 0.0f) +
                   (((unsigned)(r0 + 1) < 256u) ? wy : 0.0f);
        if (t <= e1b) acc += ux * uy;
    }
    #pragma unroll 1
    for (int base = e2a; base <= e2b; base += 16) {
        int t = base + slane;
        float tt = (float)t - TOFF;
        float x = fmaf(-tt, sa, x0);
        float y = fmaf(tt, ca, y0);
        float fx = floorf(x), fy = floorf(y);
        float wx = x - fx, wy = y - fy;
        int c0 = (int)fx, r0 = (int)fy;
        float ux = (((unsigned)c0 < 256u) ? (1.0f - wx) : 0.0f) +
                   (((unsigned)(c0 + 1) < 256u) ? wx : 0.0f);
        float uy = (((unsigned)r0 < 256u) ? (1.0f - wy) : 0.0f) +
                   (((unsigned)(r0 + 1) < 256u) ? wy : 0.0f);
        if (t <= e2b) acc += ux * uy;
    }
    acc += __shfl_down(acc, 8, 16);
    acc += __shfl_down(acc, 4, 16);
    acc += __shfl_down(acc, 2, 16);
    acc += __shfl_down(acc, 1, 16);
    if (slane == 0) minv[ray] = fmaxf(acc + (float)count, DEN_EPS);
}

// ---------------- forward projection (quad layout: 1 load = 4 corners) ---
// MODE 1: one ray/wave; diffs[ray] = (sino - FP) / Minv
// MODE 2: grid-stride; out[blockIdx.x] = block partial of sum((FP - sino)^2)
template <int MODE>
__global__ __launch_bounds__(256)
void fp_kernel(const float* __restrict__ Qn,
               const float* __restrict__ Qt,
               const float* __restrict__ sino,
               const float* __restrict__ minv,
               float* __restrict__ out,
               const float* __restrict__ cosA,
               const float* __restrict__ sinA,
               int angleStart, int angleStride, int nRays) {
    const int wid = threadIdx.x >> 6, lane = threadIdx.x & 63;
    float wacc = 0.0f;

    int ray = blockIdx.x * 4 + wid;
    if (MODE == 1 && ray >= nRays) return;
    const int rayStep = RES_BLOCKS * 4;

    for (; ray < nRays; ray += rayStep) {
        int ai = ray / NUMBIN;
        int bin = ray - ai * NUMBIN;
        int angle = angleStart + ai * angleStride;
        float ca = cosA[angle], sa = sinA[angle];
        float s = (float)bin - CDET;
        float x0 = fmaf(s, ca, CPIX);             // x(tt) = x0 - tt*sa
        float y0 = fmaf(s, sa, CPIX);             // y(tt) = y0 + tt*ca
        int itlo, nc = ray_chunks(x0, y0, ca, sa, itlo);

        bool useT = fabsf(ca) > fabsf(sa);        // wave-uniform
        const float* img = (useT ? Qt : Qn) + (QW + 1) * 2;  // origin (r=0,c=0)
        float u0 = useT ? y0 : x0, du = useT ? ca : -sa;   // fast (contiguous)
        float v0 = useT ? x0 : y0, dv = useT ? -sa : ca;   // slow (strided)

        float tt0 = (float)(itlo + lane) - TOFF;
        float u = fmaf(tt0, du, u0);
        float v = fmaf(tt0, dv, v0);
        const float du64 = du * 64.0f, dv64 = dv * 64.0f;

        float acc = 0.0f;
        for (int ic = 0; ic < nc; ic++) {
            float uc = fminf(fmaxf(u, -1.0f), 256.0f);   // tail mask + guard
            float vc = fminf(fmaxf(v, -1.0f), 256.0f);
            float fu = floorf(uc), fv = floorf(vc);
            float wu = uc - fu, wv = vc - fv;
            // exact integer fp32 index: fv*260+fu in [-261, 66816] < 2^23
            int idx = (int)fmaf(fv, (float)QW, fu);
            const float* p = img + idx * 2;
            f4q q = *(const f4q*)p;   // (v00, v10, v01, v11) in one 16B load
            float top = fmaf(wu, q.z - q.x, q.x);
            float bot = fmaf(wu, q.w - q.y, q.y);
            acc += fmaf(wv, bot - top, top);
            u += du64; v += dv64;
        }
        #pragma unroll
        for (int off = 32; off; off >>= 1) acc += __shfl_down(acc, off);
        if (lane == 0) {
            if (MODE == 1) {
                out[ray] = (sino[angle * NUMBIN + bin] - acc) /
                           minv[angle * NUMBIN + bin];
            } else {
                float d = acc - sino[angle * NUMBIN + bin];
                wacc += d * d;
            }
        }
        if (MODE == 1) break;
    }
    if (MODE == 2) {
        __shared__ float part[4];
        if (lane == 0) part[wid] = wacc;
        __syncthreads();
        if (threadIdx.x == 0)
            out[blockIdx.x] = part[0] + part[1] + part[2] + part[3];
    }
}

// ---------------- backprojection + SART update ----------------
__global__ __launch_bounds__(256)
void bp_update_kernel(float* __restrict__ fk,
                      float* __restrict__ Qf,
                      float* __restrict__ QTf,
                      const float* __restrict__ g,      // diffs [90,367]
                      const float* __restrict__ cosA,
                      const float* __restrict__ sinA,
                      int j, int doClamp) {
    __shared__ float part[4][64];
    const int tx = threadIdx.x & 63;
    const int ty = threadIdx.x >> 6;
    int p = blockIdx.x * 64 + tx;
    int px = p & (NUMPIX - 1), py = p >> 8;
    float X = (float)px - CPIX, Y = (float)py - CPIX;
    float acc = 0.0f;
    for (int i = ty; i < NANG_SUB; i += 4) {
        int angle = j + NS * i;
        float ca = cosA[angle], sa = sinA[angle];
        float sd = fmaf(X, ca, fmaf(Y, sa, CDET));   // always in [2.7, 363.3]
        float f0 = floorf(sd);
        float w = sd - f0;
        int i0 = (int)f0;
        f2u gv = *(const f2u*)(g + i * NUMBIN + i0);
        acc += fmaf(w, gv.y - gv.x, gv.x);
    }
    part[ty][tx] = acc;
    __syncthreads();
    if (ty == 0) {
        float s = part[0][tx] + part[1][tx] + part[2][tx] + part[3][tx];
        float bp = (fabsf(s) > 1000.0f) ? 0.0f : s;
        float v = fk[p] + bp * INV_DINV;
        if (doClamp) v = fmaxf(v, EPS_F);
        fk[p] = v;
        // quad-image updates: pixel (py,px) lives in 2 elements per layout
        Qf[((py + 1) * QW + (px + 1)) * 2]      = v;
        Qf[(py * QW + (px + 1)) * 2 + 1]        = v;
        QTf[((px + 1) * QW + (py + 1)) * 2]     = v;
        QTf[(px * QW + (py + 1)) * 2 + 1]       = v;
    }
}

// ---------------- select (fused residual reduce over 4096 partials) ------
__global__ __launch_bounds__(256)
void select_kernel(float* __restrict__ fcur, float* __restrict__ fk,
                   float* __restrict__ Qf, float* __restrict__ QTf,
                   const float* __restrict__ part) {
    __shared__ float buf[4];
    const int tid = threadIdx.x;
    float a = 0.0f;
    #pragma unroll
    for (int k = 0; k < RES_BLOCKS / 256; k++) a += part[tid + k * 256];
    #pragma unroll
    for (int off = 32; off; off >>= 1) a += __shfl_down(a, off);
    if ((tid & 63) == 0) buf[tid >> 6] = a;
    __syncthreads();
    float tot = buf[0] + buf[1] + buf[2] + buf[3];
    bool upd = (tot > RES2_THRESH);     // res = sqrt(res2) > 0.01
    int p = blockIdx.x * 256 + tid;
    int px = p & (NUMPIX - 1), py = p >> 8;
    float v = upd ? fk[p] : fcur[p];
    fcur[p] = v;
    fk[p] = v;
    Qf[((py + 1) * QW + (px + 1)) * 2]      = v;
    Qf[(py * QW + (px + 1)) * 2 + 1]        = v;
    QTf[((px + 1) * QW + (py + 1)) * 2]     = v;
    QTf[(px * QW + (py + 1)) * 2 + 1]       = v;
}

extern "C" void kernel_launch(void* const* d_in, const int* in_sizes, int n_in,
                              void* d_out, int out_size, void* d_ws, size_t ws_size,
                              hipStream_t stream) {
    const float* f0 = (const float*)d_in[0];     // [256,256]
    const float* sino = (const float*)d_in[1];   // [360,367]
    float* fcur = (float*)d_out;                 // [256,256] output "f"
    float* ws = (float*)d_ws;

    float* cosA = ws + OFF_COS;
    float* sinA = ws + OFF_SIN;
    float* minv = ws + OFF_MINV;   // [360,367] indexed by global angle
    float* fk   = ws + OFF_FK;     // [256,256]
    float* Qf   = ws + OFF_Q;      // quad image (normal)
    float* QTf  = ws + OFF_QT;     // quad image (transposed)
    float* diff = ws + OFF_DIFF;   // [90,367]; reused as residual partials

    init_kernel<<<(QN2 + 255) / 256, 256, 0, stream>>>(
        cosA, sinA, Qf, QTf, fk, fcur, f0);

    minv_kernel<<<(NRAYS_ALL + 15) / 16, 256, 0, stream>>>(minv, cosA, sinA);

    for (int iter = 0; iter < 2; iter++) {
        for (int j = 0; j < NS; j++) {
            fp_kernel<1><<<(NRAYS_SUB + 3) / 4, 256, 0, stream>>>(
                Qf, QTf, sino, minv, diff, cosA, sinA, j, NS, NRAYS_SUB);
            bp_update_kernel<<<NPIX2 / 64, 256, 0, stream>>>(
                fk, Qf, QTf, diff, cosA, sinA, j, (j == NS - 1) ? 1 : 0);
        }
        // residual: grid-stride partials into diff (idle here), then fused
        // reduce inside select_kernel
        fp_kernel<2><<<RES_BLOCKS, 256, 0, stream>>>(
            Qf, QTf, sino, nullptr, diff, cosA, sinA, 0, 1, NRAYS_ALL);
        select_kernel<<<NPIX2 / 256, 256, 0, stream>>>(fcur, fk, Qf, QTf, diff);
    }
}

// Round 13
// 304.404 us; speedup vs baseline: 15.1223x; 1.1917x over previous
//
#include <hip/hip_runtime.h>
#include <math.h>

#define NUMPIX 256
#define NUMBIN 367
#define NUMTHETA 360
#define NS 4
#define NT 367
#define NPIX2 (NUMPIX * NUMPIX)          // 65536
#define NRAYS_ALL (NUMTHETA * NUMBIN)    // 132120
#define NANG_SUB (NUMTHETA / NS)         // 90
#define NRAYS_SUB (NANG_SUB * NUMBIN)    // 33030

#define CDET 183.0f
#define CPIX 127.5f
#define TOFF 183.0f                      // (NT-1)/2
#define DEN_EPS 1e-6f
#define EPS_F 2.2204460492503131e-16f    // float64 eps
#define RES2_THRESH 1e-4f                // (0.01)^2
#define INV_DINV (1.0f / 90.0f)          // backproject(ones) == 90 exactly

// quad-interleaved image: element (r,c) = float2(img[r][c], img[r+1][c])
// rows r in [-1,256] stored at +1 (258 rows), cols c in [-1,258] at +1
// NOTE: sampling clamps coords to [-1,256]; the clamp is the TAIL MASK for
// overshoot lanes of the rounded-up chunk loop (clamped samples read a zero
// pad cell with weight 0 on the interior side -> contribute 0). Do NOT
// remove it (round-8 failure). Grid-wide-sync fusion abandoned (r10/r11:
// co-residency not reliable on this part).
#define QW 260                           // float2 stride
#define QROWS 258
#define QN2 (QW * QROWS)                 // 67080 float2
#define QNF (QN2 * 2)                    // 134160 floats

#define RES_BLOCKS 4096                  // MODE-2 grid (grid-stride)

typedef float f4q __attribute__((ext_vector_type(4), aligned(8)));
typedef float f2u __attribute__((ext_vector_type(2), aligned(4)));

// ---- workspace layout (in floats) ----
#define OFF_COS   0
#define OFF_SIN   (OFF_COS + NUMTHETA)           // 360
#define OFF_MINV  (OFF_SIN + NUMTHETA)           // 720
#define OFF_FK    (OFF_MINV + NRAYS_ALL)         // 132840
#define OFF_Q     (OFF_FK + NPIX2)               // 198376 (even -> float2 ok)
#define OFF_QT    (OFF_Q + QNF)                  // 332536
#define OFF_DIFF  (OFF_QT + QNF)                 // 466696 (also residual partials)

// generic t-interval clip: keep c0 + rate*tt within (bLo, bHi)
__device__ __forceinline__ void clip_axis2(float c0, float rate,
                                           float bLo, float bHi,
                                           float& lo, float& hi) {
    if (fabsf(rate) > 1e-6f) {
        float inv = 1.0f / rate;
        float a = (bLo - c0) * inv;
        float b = (bHi - c0) * inv;
        lo = fmaxf(lo, fminf(a, b));
        hi = fminf(hi, fmaxf(a, b));
    } else if (c0 <= bLo || c0 >= bHi) {
        lo = 1e9f; hi = -1e9f;
    }
}

// sampled t-range in 16-sample chunks; coords stay within clamp range
__device__ __forceinline__ int ray_chunks16(float x0, float y0, float ca, float sa,
                                            int& itlo) {
    float lo = -1e9f, hi = 1e9f;
    clip_axis2(x0, -sa, -2.0f, 257.0f, lo, hi);
    clip_axis2(y0,  ca, -2.0f, 257.0f, lo, hi);
    if (hi < lo) { itlo = 0; return 0; }
    int a = (int)floorf(lo + TOFF) - 1; if (a < 0) a = 0;
    int b = (int)ceilf(hi + TOFF) + 1;  if (b > NT - 1) b = NT - 1;
    itlo = a;
    if (b < a) return 0;
    return (b - a + 16) >> 4;
}

// ---------------- init: trig + fk/fcur + quad images ----------------
__global__ void init_kernel(float* __restrict__ cosA, float* __restrict__ sinA,
                            float* __restrict__ Qf, float* __restrict__ QTf,
                            float* __restrict__ fk, float* __restrict__ fcur,
                            const float* __restrict__ f0) {
    int idx = blockIdx.x * blockDim.x + threadIdx.x;
    if (idx < NUMTHETA) {
        float th = (float)((double)idx * 0.017453292519943295);
        cosA[idx] = (float)cos((double)th);
        sinA[idx] = (float)sin((double)th);
    }
    if (idx < NPIX2) {
        float v = f0[idx];
        fk[idx] = v;
        fcur[idx] = v;
    }
    if (idx < QN2) {
        int qr = idx / QW, qc = idx - qr * QW;
        int r = qr - 1, c = qc - 1;                 // r in [-1,256], c in [-1,258]
        bool cv = ((unsigned)c < 256u);
        bool rv0 = ((unsigned)r < 256u), rv1 = ((unsigned)(r + 1) < 256u);
        float a = (cv && rv0) ? f0[r * NUMPIX + c] : 0.0f;
        float b = (cv && rv1) ? f0[(r + 1) * NUMPIX + c] : 0.0f;
        Qf[idx * 2] = a;  Qf[idx * 2 + 1] = b;
        // transposed image: imgT(r,c) = f0[c][r]
        float ta = (cv && rv0) ? f0[c * NUMPIX + r] : 0.0f;
        float tb = (cv && rv1) ? f0[c * NUMPIX + (r + 1)] : 0.0f;
        QTf[idx * 2] = ta;  QTf[idx * 2 + 1] = tb;
    }
}

// ---------------- Minv: analytic interior count + exact edge samples -----
// 16 lanes per ray (4 rays/wave)
__global__ __launch_bounds__(256)
void minv_kernel(float* __restrict__ minv,
                 const float* __restrict__ cosA,
                 const float* __restrict__ sinA) {
    const int lane = threadIdx.x & 63;
    const int wid = threadIdx.x >> 6;
    const int sub = lane >> 4, slane = lane & 15;
    int ray = blockIdx.x * 16 + wid * 4 + sub;
    if (ray >= NRAYS_ALL) return;            // whole 16-lane group exits
    int angle = ray / NUMBIN;
    int bin = ray - angle * NUMBIN;
    float ca = cosA[angle], sa = sinA[angle];
    float s = (float)bin - CDET;
    float x0 = fmaf(s, ca, CPIX);                 // x(tt) = x0 - tt*sa
    float y0 = fmaf(s, sa, CPIX);                 // y(tt) = y0 + tt*ca
    float acc = 0.0f;
    int count = 0;
    float lo = -1e9f, hi = 1e9f;
    clip_axis2(x0, -sa, -2.0f, 257.0f, lo, hi);
    clip_axis2(y0,  ca, -2.0f, 257.0f, lo, hi);
    int e1a = 0, e1b = -1, e2a = 0, e2b = -1;
    if (hi >= lo) {
        int itA = (int)floorf(lo + TOFF) - 1; if (itA < 0) itA = 0;
        int itB = (int)ceilf(hi + TOFF) + 1;  if (itB > NT - 1) itB = NT - 1;
        if (itB >= itA) {
            // strict interior: both coords in (0.05, 254.95) -> weight exactly 1
            float ilo = -1e9f, ihi = 1e9f;
            clip_axis2(x0, -sa, 0.05f, 254.95f, ilo, ihi);
            clip_axis2(y0,  ca, 0.05f, 254.95f, ilo, ihi);
            int jA = 1, jB = 0;
            if (ihi >= ilo) {
                jA = (int)ceilf(ilo + TOFF) + 1;
                jB = (int)floorf(ihi + TOFF) - 1;
                if (jA < itA) jA = itA;
                if (jB > itB) jB = itB;
            }
            if (jB >= jA) {
                count = jB - jA + 1;
                e1a = itA; e1b = jA - 1;
                e2a = jB + 1; e2b = itB;
            } else {
                e1a = itA; e1b = itB;       // no interior: one full edge loop
            }
        }
    }
    #pragma unroll 1
    for (int base = e1a; base <= e1b; base += 16) {
        int t = base + slane;
        float tt = (float)t - TOFF;
        float x = fmaf(-tt, sa, x0);
        float y = fmaf(tt, ca, y0);
        float fx = floorf(x), fy = floorf(y);
        float wx = x - fx, wy = y - fy;
        int c0 = (int)fx, r0 = (int)fy;
        float ux = (((unsigned)c0 < 256u) ? (1.0f - wx) : 0.0f) +
                   (((unsigned)(c0 + 1) < 256u) ? wx : 0.0f);
        float uy = (((unsigned)r0 < 256u) ? (1.0f - wy) : 0.0f) +
                   (((unsigned)(r0 + 1) < 256u) ? wy : 0.0f);
        if (t <= e1b) acc += ux * uy;
    }
    #pragma unroll 1
    for (int base = e2a; base <= e2b; base += 16) {
        int t = base + slane;
        float tt = (float)t - TOFF;
        float x = fmaf(-tt, sa, x0);
        float y = fmaf(tt, ca, y0);
        float fx = floorf(x), fy = floorf(y);
        float wx = x - fx, wy = y - fy;
        int c0 = (int)fx, r0 = (int)fy;
        float ux = (((unsigned)c0 < 256u) ? (1.0f - wx) : 0.0f) +
                   (((unsigned)(c0 + 1) < 256u) ? wx : 0.0f);
        float uy = (((unsigned)r0 < 256u) ? (1.0f - wy) : 0.0f) +
                   (((unsigned)(r0 + 1) < 256u) ? wy : 0.0f);
        if (t <= e2b) acc += ux * uy;
    }
    acc += __shfl_down(acc, 8, 16);
    acc += __shfl_down(acc, 4, 16);
    acc += __shfl_down(acc, 2, 16);
    acc += __shfl_down(acc, 1, 16);
    if (slane == 0) minv[ray] = fmaxf(acc + (float)count, DEN_EPS);
}

// ---------------- forward projection: 4 rays/wave, 16 lanes each ---------
// Adjacent rays (bins b..b+3) share cache lines; 16-chunk granularity cuts
// rounded-up tail work vs 64-chunks.
// MODE 1: diffs[ray] = (sino - FP) / Minv
// MODE 2: grid-stride; out[blockIdx.x] = block partial of sum((FP - sino)^2)
template <int MODE>
__global__ __launch_bounds__(256)
void fp_kernel(const float* __restrict__ Qn,
               const float* __restrict__ Qt,
               const float* __restrict__ sino,
               const float* __restrict__ minv,
               float* __restrict__ out,
               const float* __restrict__ cosA,
               const float* __restrict__ sinA,
               int angleStart, int angleStride, int nRays) {
    const int wid = threadIdx.x >> 6, lane = threadIdx.x & 63;
    const int sub = lane >> 4, slane = lane & 15;
    float wacc = 0.0f;

    int rbase = (blockIdx.x * 4 + wid) * 4;       // 4 rays per wave
    const int rayStep = RES_BLOCKS * 16;

    for (; rbase < nRays; rbase += rayStep) {
        int ray = rbase + sub;
        bool valid = ray < nRays;
        int rr = valid ? ray : nRays - 1;
        int ai = rr / NUMBIN;
        int bin = rr - ai * NUMBIN;
        int angle = angleStart + ai * angleStride;
        float ca = cosA[angle], sa = sinA[angle];
        float s = (float)bin - CDET;
        float x0 = fmaf(s, ca, CPIX);             // x(tt) = x0 - tt*sa
        float y0 = fmaf(s, sa, CPIX);             // y(tt) = y0 + tt*ca
        int itlo, nc = ray_chunks16(x0, y0, ca, sa, itlo);
        if (!valid) nc = 0;

        bool useT = fabsf(ca) > fabsf(sa);        // uniform per sub-group
        const float* img = (useT ? Qt : Qn) + (QW + 1) * 2;  // elem (0,0)
        float u0 = useT ? y0 : x0, du = useT ? ca : -sa;   // fast (contiguous)
        float v0 = useT ? x0 : y0, dv = useT ? -sa : ca;   // slow (strided)

        float tt0 = (float)(itlo + slane) - TOFF;
        float u = fmaf(tt0, du, u0);
        float v = fmaf(tt0, dv, v0);
        const float du16 = du * 16.0f, dv16 = dv * 16.0f;

        float acc = 0.0f;
        for (int ic = 0; ic < nc; ic++) {
            float uc = fminf(fmaxf(u, -1.0f), 256.0f);   // tail mask + guard
            float vc = fminf(fmaxf(v, -1.0f), 256.0f);
            float fu = floorf(uc), fv = floorf(vc);
            float wu = uc - fu, wv = vc - fv;
            // exact integer fp32 index: fv*260+fu in [-261, 66816] < 2^23
            int idx = (int)fmaf(fv, (float)QW, fu);
            const float* p = img + idx * 2;
            f4q q = *(const f4q*)p;   // (v00, v10, v01, v11) in one 16B load
            float top = fmaf(wu, q.z - q.x, q.x);
            float bot = fmaf(wu, q.w - q.y, q.y);
            acc += fmaf(wv, bot - top, top);
            u += du16; v += dv16;
        }
        acc += __shfl_down(acc, 8, 16);
        acc += __shfl_down(acc, 4, 16);
        acc += __shfl_down(acc, 2, 16);
        acc += __shfl_down(acc, 1, 16);
        if (slane == 0 && valid) {
            if (MODE == 1) {
                out[ray] = (sino[angle * NUMBIN + bin] - acc) /
                           minv[angle * NUMBIN + bin];
            } else {
                float d = acc - sino[angle * NUMBIN + bin];
                wacc += d * d;
            }
        }
        if (MODE == 1) break;
    }
    if (MODE == 2) {
        // wacc lives on lanes 0/16/32/48 of each wave
        wacc += __shfl_down(wacc, 16);
        wacc += __shfl_down(wacc, 32);
        __shared__ float part[4];
        if (lane == 0) part[wid] = wacc;
        __syncthreads();
        if (threadIdx.x == 0)
            out[blockIdx.x] = part[0] + part[1] + part[2] + part[3];
    }
}

// ---------------- backprojection + SART update ----------------
__global__ __launch_bounds__(256)
void bp_update_kernel(float* __restrict__ fk,
                      float* __restrict__ Qf,
                      float* __restrict__ QTf,
                      const float* __restrict__ g,      // diffs [90,367]
                      const float* __restrict__ cosA,
                      const float* __restrict__ sinA,
                      int j, int doClamp) {
    __shared__ float part[4][64];
    const int tx = threadIdx.x & 63;
    const int ty = threadIdx.x >> 6;
    int p = blockIdx.x * 64 + tx;
    int px = p & (NUMPIX - 1), py = p >> 8;
    float X = (float)px - CPIX, Y = (float)py - CPIX;
    float acc = 0.0f;
    for (int i = ty; i < NANG_SUB; i += 4) {
        int angle = j + NS * i;
        float ca = cosA[angle], sa = sinA[angle];
        float sd = fmaf(X, ca, fmaf(Y, sa, CDET));   // always in [2.7, 363.3]
        float f0 = floorf(sd);
        float w = sd - f0;
        int i0 = (int)f0;
        f2u gv = *(const f2u*)(g + i * NUMBIN + i0);
        acc += fmaf(w, gv.y - gv.x, gv.x);
    }
    part[ty][tx] = acc;
    __syncthreads();
    if (ty == 0) {
        float s = part[0][tx] + part[1][tx] + part[2][tx] + part[3][tx];
        float bp = (fabsf(s) > 1000.0f) ? 0.0f : s;
        float v = fk[p] + bp * INV_DINV;
        if (doClamp) v = fmaxf(v, EPS_F);
        fk[p] = v;
        // quad-image updates: pixel (py,px) lives in 2 elements per layout
        Qf[((py + 1) * QW + (px + 1)) * 2]      = v;
        Qf[(py * QW + (px + 1)) * 2 + 1]        = v;
        QTf[((px + 1) * QW + (py + 1)) * 2]     = v;
        QTf[(px * QW + (py + 1)) * 2 + 1]       = v;
    }
}

// ---------------- select (fused residual reduce over 4096 partials) ------
__global__ __launch_bounds__(256)
void select_kernel(float* __restrict__ fcur, float* __restrict__ fk,
                   float* __restrict__ Qf, float* __restrict__ QTf,
                   const float* __restrict__ part) {
    __shared__ float buf[4];
    const int tid = threadIdx.x;
    float a = 0.0f;
    #pragma unroll
    for (int k = 0; k < RES_BLOCKS / 256; k++) a += part[tid + k * 256];
    #pragma unroll
    for (int off = 32; off; off >>= 1) a += __shfl_down(a, off);
    if ((tid & 63) == 0) buf[tid >> 6] = a;
    __syncthreads();
    float tot = buf[0] + buf[1] + buf[2] + buf[3];
    bool upd = (tot > RES2_THRESH);     // res = sqrt(res2) > 0.01
    int p = blockIdx.x * 256 + tid;
    int px = p & (NUMPIX - 1), py = p >> 8;
    float v = upd ? fk[p] : fcur[p];
    fcur[p] = v;
    fk[p] = v;
    Qf[((py + 1) * QW + (px + 1)) * 2]      = v;
    Qf[(py * QW + (px + 1)) * 2 + 1]        = v;
    QTf[((px + 1) * QW + (py + 1)) * 2]     = v;
    QTf[(px * QW + (py + 1)) * 2 + 1]       = v;
}

extern "C" void kernel_launch(void* const* d_in, const int* in_sizes, int n_in,
                              void* d_out, int out_size, void* d_ws, size_t ws_size,
                              hipStream_t stream) {
    const float* f0 = (const float*)d_in[0];     // [256,256]
    const float* sino = (const float*)d_in[1];   // [360,367]
    float* fcur = (float*)d_out;                 // [256,256] output "f"
    float* ws = (float*)d_ws;

    float* cosA = ws + OFF_COS;
    float* sinA = ws + OFF_SIN;
    float* minv = ws + OFF_MINV;   // [360,367] indexed by global angle
    float* fk   = ws + OFF_FK;     // [256,256]
    float* Qf   = ws + OFF_Q;      // quad image (normal)
    float* QTf  = ws + OFF_QT;     // quad image (transposed)
    float* diff = ws + OFF_DIFF;   // [90,367]; reused as residual partials

    init_kernel<<<(QN2 + 255) / 256, 256, 0, stream>>>(
        cosA, sinA, Qf, QTf, fk, fcur, f0);

    minv_kernel<<<(NRAYS_ALL + 15) / 16, 256, 0, stream>>>(minv, cosA, sinA);

    for (int iter = 0; iter < 2; iter++) {
        for (int j = 0; j < NS; j++) {
            fp_kernel<1><<<(NRAYS_SUB + 15) / 16, 256, 0, stream>>>(
                Qf, QTf, sino, minv, diff, cosA, sinA, j, NS, NRAYS_SUB);
            bp_update_kernel<<<NPIX2 / 64, 256, 0, stream>>>(
                fk, Qf, QTf, diff, cosA, sinA, j, (j == NS - 1) ? 1 : 0);
        }
        // residual: grid-stride partials into diff (idle here), then fused
        // reduce inside select_kernel
        fp_kernel<2><<<RES_BLOCKS, 256, 0, stream>>>(
            Qf, QTf, sino, nullptr, diff, cosA, sinA, 0, 1, NRAYS_ALL);
        select_kernel<<<NPIX2 / 256, 256, 0, stream>>>(fcur, fk, Qf, QTf, diff);
    }
}

// Round 14
// 303.901 us; speedup vs baseline: 15.1474x; 1.0017x over previous
//
#include <hip/hip_runtime.h>
#include <math.h>

#define NUMPIX 256
#define NUMBIN 367
#define NUMTHETA 360
#define NS 4
#define NT 367
#define NPIX2 (NUMPIX * NUMPIX)          // 65536
#define NRAYS_ALL (NUMTHETA * NUMBIN)    // 132120
#define NANG_SUB (NUMTHETA / NS)         // 90
#define NRAYS_SUB (NANG_SUB * NUMBIN)    // 33030

#define CDET 183.0f
#define CPIX 127.5f
#define TOFF 183.0f                      // (NT-1)/2
#define DEN_EPS 1e-6f
#define EPS_F 2.2204460492503131e-16f    // float64 eps
#define RES2_THRESH 1e-4f                // (0.01)^2
#define INV_DINV (1.0f / 90.0f)          // backproject(ones) == 90 exactly

// quad-interleaved image: element (r,c) = float2(img[r][c], img[r+1][c])
// rows r in [-1,256] stored at +1 (258 rows), cols c in [-1,258] at +1
// NOTE: sampling clamps coords to [-1,256]; the clamp is the TAIL MASK for
// overshoot lanes of the rounded-up chunk loop (clamped samples read a zero
// pad cell with weight 0 on the interior side -> contribute 0). Do NOT
// remove it (round-8 failure). Grid-wide-sync fusion abandoned (r10/r11:
// co-residency not reliable on this part).
#define QW 260                           // float2 stride
#define QROWS 258
#define QN2 (QW * QROWS)                 // 67080 float2
#define QNF (QN2 * 2)                    // 134160 floats

// exact-cover grids: 4 rays/wave, 4 waves/block -> 16 rays/block
#define RES_BLOCKS ((NRAYS_ALL + 15) / 16)   // 8258
#define SUB_BLOCKS ((NRAYS_SUB + 15) / 16)   // 2065

typedef float f4q __attribute__((ext_vector_type(4), aligned(8)));
typedef float f2u __attribute__((ext_vector_type(2), aligned(4)));

// ---- workspace layout (in floats) ----
#define OFF_COS   0
#define OFF_SIN   (OFF_COS + NUMTHETA)           // 360
#define OFF_MINV  (OFF_SIN + NUMTHETA)           // 720
#define OFF_FK    (OFF_MINV + NRAYS_ALL)         // 132840
#define OFF_Q     (OFF_FK + NPIX2)               // 198376 (even -> float2 ok)
#define OFF_QT    (OFF_Q + QNF)                  // 332536
#define OFF_DIFF  (OFF_QT + QNF)                 // 466696 (also residual partials)

// generic t-interval clip: keep c0 + rate*tt within (bLo, bHi)
__device__ __forceinline__ void clip_axis2(float c0, float rate,
                                           float bLo, float bHi,
                                           float& lo, float& hi) {
    if (fabsf(rate) > 1e-6f) {
        float inv = 1.0f / rate;
        float a = (bLo - c0) * inv;
        float b = (bHi - c0) * inv;
        lo = fmaxf(lo, fminf(a, b));
        hi = fminf(hi, fmaxf(a, b));
    } else if (c0 <= bLo || c0 >= bHi) {
        lo = 1e9f; hi = -1e9f;
    }
}

// sampled t-range in 16-sample chunks; coords stay within clamp range
__device__ __forceinline__ int ray_chunks16(float x0, float y0, float ca, float sa,
                                            int& itlo) {
    float lo = -1e9f, hi = 1e9f;
    clip_axis2(x0, -sa, -2.0f, 257.0f, lo, hi);
    clip_axis2(y0,  ca, -2.0f, 257.0f, lo, hi);
    if (hi < lo) { itlo = 0; return 0; }
    int a = (int)floorf(lo + TOFF) - 1; if (a < 0) a = 0;
    int b = (int)ceilf(hi + TOFF) + 1;  if (b > NT - 1) b = NT - 1;
    itlo = a;
    if (b < a) return 0;
    return (b - a + 16) >> 4;
}

// ---------------- init: trig + fk/fcur + quad images ----------------
__global__ void init_kernel(float* __restrict__ cosA, float* __restrict__ sinA,
                            float* __restrict__ Qf, float* __restrict__ QTf,
                            float* __restrict__ fk, float* __restrict__ fcur,
                            const float* __restrict__ f0) {
    int idx = blockIdx.x * blockDim.x + threadIdx.x;
    if (idx < NUMTHETA) {
        float th = (float)((double)idx * 0.017453292519943295);
        cosA[idx] = (float)cos((double)th);
        sinA[idx] = (float)sin((double)th);
    }
    if (idx < NPIX2) {
        float v = f0[idx];
        fk[idx] = v;
        fcur[idx] = v;
    }
    if (idx < QN2) {
        int qr = idx / QW, qc = idx - qr * QW;
        int r = qr - 1, c = qc - 1;                 // r in [-1,256], c in [-1,258]
        bool cv = ((unsigned)c < 256u);
        bool rv0 = ((unsigned)r < 256u), rv1 = ((unsigned)(r + 1) < 256u);
        float a = (cv && rv0) ? f0[r * NUMPIX + c] : 0.0f;
        float b = (cv && rv1) ? f0[(r + 1) * NUMPIX + c] : 0.0f;
        Qf[idx * 2] = a;  Qf[idx * 2 + 1] = b;
        // transposed image: imgT(r,c) = f0[c][r]
        float ta = (cv && rv0) ? f0[c * NUMPIX + r] : 0.0f;
        float tb = (cv && rv1) ? f0[c * NUMPIX + (r + 1)] : 0.0f;
        QTf[idx * 2] = ta;  QTf[idx * 2 + 1] = tb;
    }
}

// ---------------- Minv: analytic interior count + exact edge samples -----
// 16 lanes per ray (4 rays/wave)
__global__ __launch_bounds__(256)
void minv_kernel(float* __restrict__ minv,
                 const float* __restrict__ cosA,
                 const float* __restrict__ sinA) {
    const int lane = threadIdx.x & 63;
    const int wid = threadIdx.x >> 6;
    const int sub = lane >> 4, slane = lane & 15;
    int ray = blockIdx.x * 16 + wid * 4 + sub;
    if (ray >= NRAYS_ALL) return;            // whole 16-lane group exits
    int angle = ray / NUMBIN;
    int bin = ray - angle * NUMBIN;
    float ca = cosA[angle], sa = sinA[angle];
    float s = (float)bin - CDET;
    float x0 = fmaf(s, ca, CPIX);                 // x(tt) = x0 - tt*sa
    float y0 = fmaf(s, sa, CPIX);                 // y(tt) = y0 + tt*ca
    float acc = 0.0f;
    int count = 0;
    float lo = -1e9f, hi = 1e9f;
    clip_axis2(x0, -sa, -2.0f, 257.0f, lo, hi);
    clip_axis2(y0,  ca, -2.0f, 257.0f, lo, hi);
    int e1a = 0, e1b = -1, e2a = 0, e2b = -1;
    if (hi >= lo) {
        int itA = (int)floorf(lo + TOFF) - 1; if (itA < 0) itA = 0;
        int itB = (int)ceilf(hi + TOFF) + 1;  if (itB > NT - 1) itB = NT - 1;
        if (itB >= itA) {
            // strict interior: both coords in (0.05, 254.95) -> weight exactly 1
            float ilo = -1e9f, ihi = 1e9f;
            clip_axis2(x0, -sa, 0.05f, 254.95f, ilo, ihi);
            clip_axis2(y0,  ca, 0.05f, 254.95f, ilo, ihi);
            int jA = 1, jB = 0;
            if (ihi >= ilo) {
                jA = (int)ceilf(ilo + TOFF) + 1;
                jB = (int)floorf(ihi + TOFF) - 1;
                if (jA < itA) jA = itA;
                if (jB > itB) jB = itB;
            }
            if (jB >= jA) {
                count = jB - jA + 1;
                e1a = itA; e1b = jA - 1;
                e2a = jB + 1; e2b = itB;
            } else {
                e1a = itA; e1b = itB;       // no interior: one full edge loop
            }
        }
    }
    #pragma unroll 1
    for (int base = e1a; base <= e1b; base += 16) {
        int t = base + slane;
        float tt = (float)t - TOFF;
        float x = fmaf(-tt, sa, x0);
        float y = fmaf(tt, ca, y0);
        float fx = floorf(x), fy = floorf(y);
        float wx = x - fx, wy = y - fy;
        int c0 = (int)fx, r0 = (int)fy;
        float ux = (((unsigned)c0 < 256u) ? (1.0f - wx) : 0.0f) +
                   (((unsigned)(c0 + 1) < 256u) ? wx : 0.0f);
        float uy = (((unsigned)r0 < 256u) ? (1.0f - wy) : 0.0f) +
                   (((unsigned)(r0 + 1) < 256u) ? wy : 0.0f);
        if (t <= e1b) acc += ux * uy;
    }
    #pragma unroll 1
    for (int base = e2a; base <= e2b; base += 16) {
        int t = base + slane;
        float tt = (float)t - TOFF;
        float x = fmaf(-tt, sa, x0);
        float y = fmaf(tt, ca, y0);
        float fx = floorf(x), fy = floorf(y);
        float wx = x - fx, wy = y - fy;
        int c0 = (int)fx, r0 = (int)fy;
        float ux = (((unsigned)c0 < 256u) ? (1.0f - wx) : 0.0f) +
                   (((unsigned)(c0 + 1) < 256u) ? wx : 0.0f);
        float uy = (((unsigned)r0 < 256u) ? (1.0f - wy) : 0.0f) +
                   (((unsigned)(r0 + 1) < 256u) ? wy : 0.0f);
        if (t <= e2b) acc += ux * uy;
    }
    acc += __shfl_down(acc, 8, 16);
    acc += __shfl_down(acc, 4, 16);
    acc += __shfl_down(acc, 2, 16);
    acc += __shfl_down(acc, 1, 16);
    if (slane == 0) minv[ray] = fmaxf(acc + (float)count, DEN_EPS);
}

// ---------------- forward projection: 4 rays/wave, 16 lanes each ---------
// Exact-cover grid (no grid-stride); chunk loop unrolled x2 with dual
// accumulators so two gathers are in flight per wave (MLP).
// MODE 1: diffs[ray] = (sino - FP) / Minv
// MODE 2: out[blockIdx.x] = block partial of sum((FP - sino)^2)
template <int MODE>
__global__ __launch_bounds__(256)
void fp_kernel(const float* __restrict__ Qn,
               const float* __restrict__ Qt,
               const float* __restrict__ sino,
               const float* __restrict__ minv,
               float* __restrict__ out,
               const float* __restrict__ cosA,
               const float* __restrict__ sinA,
               int angleStart, int angleStride, int nRays) {
    const int wid = threadIdx.x >> 6, lane = threadIdx.x & 63;
    const int sub = lane >> 4, slane = lane & 15;

    int ray = (blockIdx.x * 4 + wid) * 4 + sub;
    bool valid = ray < nRays;
    int rr = valid ? ray : nRays - 1;
    int ai = rr / NUMBIN;
    int bin = rr - ai * NUMBIN;
    int angle = angleStart + ai * angleStride;
    float ca = cosA[angle], sa = sinA[angle];
    float s = (float)bin - CDET;
    float x0 = fmaf(s, ca, CPIX);             // x(tt) = x0 - tt*sa
    float y0 = fmaf(s, sa, CPIX);             // y(tt) = y0 + tt*ca
    int itlo, nc = ray_chunks16(x0, y0, ca, sa, itlo);
    if (!valid) nc = 0;

    bool useT = fabsf(ca) > fabsf(sa);        // uniform per sub-group
    const float* img = (useT ? Qt : Qn) + (QW + 1) * 2;  // elem (0,0)
    float u0 = useT ? y0 : x0, du = useT ? ca : -sa;   // fast (contiguous)
    float v0 = useT ? x0 : y0, dv = useT ? -sa : ca;   // slow (strided)

    float tt0 = (float)(itlo + slane) - TOFF;
    float u = fmaf(tt0, du, u0);
    float v = fmaf(tt0, dv, v0);
    const float du16 = du * 16.0f, dv16 = dv * 16.0f;
    const float du32 = du * 32.0f, dv32 = dv * 32.0f;

    float acc0 = 0.0f, acc1 = 0.0f;
    int ic = 0;
    for (; ic + 1 < nc; ic += 2) {
        // chunk A at (u,v); chunk B at (u+du16, v+dv16) — independent loads
        float uA = fminf(fmaxf(u, -1.0f), 256.0f);
        float vA = fminf(fmaxf(v, -1.0f), 256.0f);
        float uB = fminf(fmaxf(u + du16, -1.0f), 256.0f);
        float vB = fminf(fmaxf(v + dv16, -1.0f), 256.0f);
        float fuA = floorf(uA), fvA = floorf(vA);
        float fuB = floorf(uB), fvB = floorf(vB);
        float wuA = uA - fuA, wvA = vA - fvA;
        float wuB = uB - fuB, wvB = vB - fvB;
        int idxA = (int)fmaf(fvA, (float)QW, fuA);
        int idxB = (int)fmaf(fvB, (float)QW, fuB);
        f4q qA = *(const f4q*)(img + idxA * 2);
        f4q qB = *(const f4q*)(img + idxB * 2);
        float topA = fmaf(wuA, qA.z - qA.x, qA.x);
        float botA = fmaf(wuA, qA.w - qA.y, qA.y);
        acc0 += fmaf(wvA, botA - topA, topA);
        float topB = fmaf(wuB, qB.z - qB.x, qB.x);
        float botB = fmaf(wuB, qB.w - qB.y, qB.y);
        acc1 += fmaf(wvB, botB - topB, topB);
        u += du32; v += dv32;
    }
    if (ic < nc) {
        float uc = fminf(fmaxf(u, -1.0f), 256.0f);
        float vc = fminf(fmaxf(v, -1.0f), 256.0f);
        float fu = floorf(uc), fv = floorf(vc);
        float wu = uc - fu, wv = vc - fv;
        int idx = (int)fmaf(fv, (float)QW, fu);
        f4q q = *(const f4q*)(img + idx * 2);
        float top = fmaf(wu, q.z - q.x, q.x);
        float bot = fmaf(wu, q.w - q.y, q.y);
        acc0 += fmaf(wv, bot - top, top);
    }
    float acc = acc0 + acc1;
    acc += __shfl_down(acc, 8, 16);
    acc += __shfl_down(acc, 4, 16);
    acc += __shfl_down(acc, 2, 16);
    acc += __shfl_down(acc, 1, 16);

    if (MODE == 1) {
        if (slane == 0 && valid)
            out[ray] = (sino[angle * NUMBIN + bin] - acc) /
                       minv[angle * NUMBIN + bin];
    } else {
        float d2 = 0.0f;
        if (slane == 0 && valid) {
            float d = acc - sino[angle * NUMBIN + bin];
            d2 = d * d;
        }
        // d2 lives on lanes 0/16/32/48 of each wave
        d2 += __shfl_down(d2, 16);
        d2 += __shfl_down(d2, 32);
        __shared__ float part[4];
        if (lane == 0) part[wid] = d2;
        __syncthreads();
        if (threadIdx.x == 0)
            out[blockIdx.x] = part[0] + part[1] + part[2] + part[3];
    }
}

// ---------------- backprojection + SART update ----------------
__global__ __launch_bounds__(256)
void bp_update_kernel(float* __restrict__ fk,
                      float* __restrict__ Qf,
                      float* __restrict__ QTf,
                      const float* __restrict__ g,      // diffs [90,367]
                      const float* __restrict__ cosA,
                      const float* __restrict__ sinA,
                      int j, int doClamp) {
    __shared__ float part[4][64];
    const int tx = threadIdx.x & 63;
    const int ty = threadIdx.x >> 6;
    int p = blockIdx.x * 64 + tx;
    int px = p & (NUMPIX - 1), py = p >> 8;
    float X = (float)px - CPIX, Y = (float)py - CPIX;
    float acc = 0.0f;
    for (int i = ty; i < NANG_SUB; i += 4) {
        int angle = j + NS * i;
        float ca = cosA[angle], sa = sinA[angle];
        float sd = fmaf(X, ca, fmaf(Y, sa, CDET));   // always in [2.7, 363.3]
        float f0 = floorf(sd);
        float w = sd - f0;
        int i0 = (int)f0;
        f2u gv = *(const f2u*)(g + i * NUMBIN + i0);
        acc += fmaf(w, gv.y - gv.x, gv.x);
    }
    part[ty][tx] = acc;
    __syncthreads();
    if (ty == 0) {
        float s = part[0][tx] + part[1][tx] + part[2][tx] + part[3][tx];
        float bp = (fabsf(s) > 1000.0f) ? 0.0f : s;
        float v = fk[p] + bp * INV_DINV;
        if (doClamp) v = fmaxf(v, EPS_F);
        fk[p] = v;
        // quad-image updates: pixel (py,px) lives in 2 elements per layout
        Qf[((py + 1) * QW + (px + 1)) * 2]      = v;
        Qf[(py * QW + (px + 1)) * 2 + 1]        = v;
        QTf[((px + 1) * QW + (py + 1)) * 2]     = v;
        QTf[(px * QW + (py + 1)) * 2 + 1]       = v;
    }
}

// ---------------- select (fused residual reduce over 8258 partials) ------
__global__ __launch_bounds__(256)
void select_kernel(float* __restrict__ fcur, float* __restrict__ fk,
                   float* __restrict__ Qf, float* __restrict__ QTf,
                   const float* __restrict__ part) {
    __shared__ float buf[4];
    const int tid = threadIdx.x;
    float a = 0.0f;
    for (int idx = tid; idx < RES_BLOCKS; idx += 256) a += part[idx];
    #pragma unroll
    for (int off = 32; off; off >>= 1) a += __shfl_down(a, off);
    if ((tid & 63) == 0) buf[tid >> 6] = a;
    __syncthreads();
    float tot = buf[0] + buf[1] + buf[2] + buf[3];
    bool upd = (tot > RES2_THRESH);     // res = sqrt(res2) > 0.01
    int p = blockIdx.x * 256 + tid;
    int px = p & (NUMPIX - 1), py = p >> 8;
    float v = upd ? fk[p] : fcur[p];
    fcur[p] = v;
    fk[p] = v;
    Qf[((py + 1) * QW + (px + 1)) * 2]      = v;
    Qf[(py * QW + (px + 1)) * 2 + 1]        = v;
    QTf[((px + 1) * QW + (py + 1)) * 2]     = v;
    QTf[(px * QW + (py + 1)) * 2 + 1]       = v;
}

extern "C" void kernel_launch(void* const* d_in, const int* in_sizes, int n_in,
                              void* d_out, int out_size, void* d_ws, size_t ws_size,
                              hipStream_t stream) {
    const float* f0 = (const float*)d_in[0];     // [256,256]
    const float* sino = (const float*)d_in[1];   // [360,367]
    float* fcur = (float*)d_out;                 // [256,256] output "f"
    float* ws = (float*)d_ws;

    float* cosA = ws + OFF_COS;
    float* sinA = ws + OFF_SIN;
    float* minv = ws + OFF_MINV;   // [360,367] indexed by global angle
    float* fk   = ws + OFF_FK;     // [256,256]
    float* Qf   = ws + OFF_Q;      // quad image (normal)
    float* QTf  = ws + OFF_QT;     // quad image (transposed)
    float* diff = ws + OFF_DIFF;   // [90,367]; reused as residual partials

    init_kernel<<<(QN2 + 255) / 256, 256, 0, stream>>>(
        cosA, sinA, Qf, QTf, fk, fcur, f0);

    minv_kernel<<<(NRAYS_ALL + 15) / 16, 256, 0, stream>>>(minv, cosA, sinA);

    for (int iter = 0; iter < 2; iter++) {
        for (int j = 0; j < NS; j++) {
            fp_kernel<1><<<SUB_BLOCKS, 256, 0, stream>>>(
                Qf, QTf, sino, minv, diff, cosA, sinA, j, NS, NRAYS_SUB);
            bp_update_kernel<<<NPIX2 / 64, 256, 0, stream>>>(
                fk, Qf, QTf, diff, cosA, sinA, j, (j == NS - 1) ? 1 : 0);
        }
        // residual: per-block partials into diff (idle here), then fused
        // reduce inside select_kernel
        fp_kernel<2><<<RES_BLOCKS, 256, 0, stream>>>(
            Qf, QTf, sino, nullptr, diff, cosA, sinA, 0, 1, NRAYS_ALL);
        select_kernel<<<NPIX2 / 256, 256, 0, stream>>>(fcur, fk, Qf, QTf, diff);
    }
}

// Round 15
// 298.371 us; speedup vs baseline: 15.4281x; 1.0185x over previous
//
#include <hip/hip_runtime.h>
#include <math.h>

#define NUMPIX 256
#define NUMBIN 367
#define NUMTHETA 360
#define NS 4
#define NT 367
#define NPIX2 (NUMPIX * NUMPIX)          // 65536
#define NRAYS_ALL (NUMTHETA * NUMBIN)    // 132120
#define NANG_SUB (NUMTHETA / NS)         // 90
#define NRAYS_SUB (NANG_SUB * NUMBIN)    // 33030

#define CDET 183.0f
#define CPIX 127.5f
#define TOFF 183.0f                      // (NT-1)/2
#define DEN_EPS 1e-6f
#define EPS_F 2.2204460492503131e-16f    // float64 eps
#define RES2_THRESH 1e-4f                // (0.01)^2
#define INV_DINV (1.0f / 90.0f)          // backproject(ones) == 90 exactly

// quad-interleaved image: element (r,c) = float2(img[r][c], img[r+1][c])
// rows r in [-1,256] stored at +1 (258 rows), cols c in [-1,258] at +1
// Pixel (py,px) value lives at Qf[(py+1)*QW+px+1].x (also .y of the row
// above) — used as the canonical fk storage (no separate fk buffer).
// NOTE: sampling clamps coords to [-1,256]; the clamp is the TAIL MASK for
// overshoot lanes of the rounded-up chunk loop (clamped samples read a zero
// pad cell with weight 0 on the interior side -> contribute 0). Do NOT
// remove it (round-8 failure). Grid-wide-sync fusion abandoned (r10/r11:
// co-residency not reliable on this part).
#define QW 260                           // float2 stride
#define QROWS 258
#define QN2 (QW * QROWS)                 // 67080 float2
#define QNF (QN2 * 2)                    // 134160 floats

// exact-cover grids: 4 rays/wave, 4 waves/block -> 16 rays/block
#define RES_BLOCKS ((NRAYS_ALL + 15) / 16)   // 8258
#define SUB_BLOCKS ((NRAYS_SUB + 15) / 16)   // 2065

typedef float f4q __attribute__((ext_vector_type(4), aligned(8)));
typedef float f2u __attribute__((ext_vector_type(2), aligned(4)));

// ---- workspace layout (in floats) ----
#define OFF_COS   0
#define OFF_SIN   (OFF_COS + NUMTHETA)           // 360
#define OFF_MINV  (OFF_SIN + NUMTHETA)           // 720
#define OFF_Q     (OFF_MINV + NRAYS_ALL + 8)     // even-aligned
#define OFF_QT    (OFF_Q + QNF)
#define OFF_DIFF  (OFF_QT + QNF)                 // diffs / residual partials

// generic t-interval clip: keep c0 + rate*tt within (bLo, bHi)
__device__ __forceinline__ void clip_axis2(float c0, float rate,
                                           float bLo, float bHi,
                                           float& lo, float& hi) {
    if (fabsf(rate) > 1e-6f) {
        float inv = 1.0f / rate;
        float a = (bLo - c0) * inv;
        float b = (bHi - c0) * inv;
        lo = fmaxf(lo, fminf(a, b));
        hi = fminf(hi, fmaxf(a, b));
    } else if (c0 <= bLo || c0 >= bHi) {
        lo = 1e9f; hi = -1e9f;
    }
}

// sampled t-range in 16-sample chunks; coords stay within clamp range
__device__ __forceinline__ int ray_chunks16(float x0, float y0, float ca, float sa,
                                            int& itlo) {
    float lo = -1e9f, hi = 1e9f;
    clip_axis2(x0, -sa, -2.0f, 257.0f, lo, hi);
    clip_axis2(y0,  ca, -2.0f, 257.0f, lo, hi);
    if (hi < lo) { itlo = 0; return 0; }
    int a = (int)floorf(lo + TOFF) - 1; if (a < 0) a = 0;
    int b = (int)ceilf(hi + TOFF) + 1;  if (b > NT - 1) b = NT - 1;
    itlo = a;
    if (b < a) return 0;
    return (b - a + 16) >> 4;
}

// ---------------- init + Minv in one dispatch ----------------
// Blocks cover max(QN2/256, RES_BLOCKS). Init portion (idx-gated) builds
// trig tables, fcur, quad images. Minv portion (block-gated) computes its
// own per-ray trig via __sincosf (normalizer only; ~1e-6 rel perturbation,
// 20x under the absmax threshold) so there is no cross-block dependency.
__global__ __launch_bounds__(256)
void init_minv_kernel(float* __restrict__ cosA, float* __restrict__ sinA,
                      float* __restrict__ Qf, float* __restrict__ QTf,
                      float* __restrict__ fcur, float* __restrict__ minv,
                      const float* __restrict__ f0) {
    int idx = blockIdx.x * blockDim.x + threadIdx.x;
    if (idx < NUMTHETA) {
        float th = (float)((double)idx * 0.017453292519943295);
        cosA[idx] = (float)cos((double)th);
        sinA[idx] = (float)sin((double)th);
    }
    if (idx < NPIX2) fcur[idx] = f0[idx];
    if (idx < QN2) {
        int qr = idx / QW, qc = idx - qr * QW;
        int r = qr - 1, c = qc - 1;                 // r in [-1,256], c in [-1,258]
        bool cv = ((unsigned)c < 256u);
        bool rv0 = ((unsigned)r < 256u), rv1 = ((unsigned)(r + 1) < 256u);
        float a = (cv && rv0) ? f0[r * NUMPIX + c] : 0.0f;
        float b = (cv && rv1) ? f0[(r + 1) * NUMPIX + c] : 0.0f;
        Qf[idx * 2] = a;  Qf[idx * 2 + 1] = b;
        // transposed image: imgT(r,c) = f0[c][r]
        float ta = (cv && rv0) ? f0[c * NUMPIX + r] : 0.0f;
        float tb = (cv && rv1) ? f0[c * NUMPIX + (r + 1)] : 0.0f;
        QTf[idx * 2] = ta;  QTf[idx * 2 + 1] = tb;
    }

    // ---- Minv portion: 16 lanes per ray, 4 rays/wave, 16 rays/block
    const int lane = threadIdx.x & 63;
    const int wid = threadIdx.x >> 6;
    const int sub = lane >> 4, slane = lane & 15;
    int ray = blockIdx.x * 16 + wid * 4 + sub;
    if (ray >= NRAYS_ALL) return;            // whole 16-lane group exits
    int angle = ray / NUMBIN;
    int bin = ray - angle * NUMBIN;
    float th = (float)((double)angle * 0.017453292519943295);
    float ca, sa;
    __sincosf(th, &sa, &ca);
    float s = (float)bin - CDET;
    float x0 = fmaf(s, ca, CPIX);                 // x(tt) = x0 - tt*sa
    float y0 = fmaf(s, sa, CPIX);                 // y(tt) = y0 + tt*ca
    float acc = 0.0f;
    int count = 0;
    float lo = -1e9f, hi = 1e9f;
    clip_axis2(x0, -sa, -2.0f, 257.0f, lo, hi);
    clip_axis2(y0,  ca, -2.0f, 257.0f, lo, hi);
    int e1a = 0, e1b = -1, e2a = 0, e2b = -1;
    if (hi >= lo) {
        int itA = (int)floorf(lo + TOFF) - 1; if (itA < 0) itA = 0;
        int itB = (int)ceilf(hi + TOFF) + 1;  if (itB > NT - 1) itB = NT - 1;
        if (itB >= itA) {
            // strict interior: both coords in (0.05, 254.95) -> weight exactly 1
            float ilo = -1e9f, ihi = 1e9f;
            clip_axis2(x0, -sa, 0.05f, 254.95f, ilo, ihi);
            clip_axis2(y0,  ca, 0.05f, 254.95f, ilo, ihi);
            int jA = 1, jB = 0;
            if (ihi >= ilo) {
                jA = (int)ceilf(ilo + TOFF) + 1;
                jB = (int)floorf(ihi + TOFF) - 1;
                if (jA < itA) jA = itA;
                if (jB > itB) jB = itB;
            }
            if (jB >= jA) {
                count = jB - jA + 1;
                e1a = itA; e1b = jA - 1;
                e2a = jB + 1; e2b = itB;
            } else {
                e1a = itA; e1b = itB;       // no interior: one full edge loop
            }
        }
    }
    #pragma unroll 1
    for (int base = e1a; base <= e1b; base += 16) {
        int t = base + slane;
        float tt = (float)t - TOFF;
        float x = fmaf(-tt, sa, x0);
        float y = fmaf(tt, ca, y0);
        float fx = floorf(x), fy = floorf(y);
        float wx = x - fx, wy = y - fy;
        int c0 = (int)fx, r0 = (int)fy;
        float ux = (((unsigned)c0 < 256u) ? (1.0f - wx) : 0.0f) +
                   (((unsigned)(c0 + 1) < 256u) ? wx : 0.0f);
        float uy = (((unsigned)r0 < 256u) ? (1.0f - wy) : 0.0f) +
                   (((unsigned)(r0 + 1) < 256u) ? wy : 0.0f);
        if (t <= e1b) acc += ux * uy;
    }
    #pragma unroll 1
    for (int base = e2a; base <= e2b; base += 16) {
        int t = base + slane;
        float tt = (float)t - TOFF;
        float x = fmaf(-tt, sa, x0);
        float y = fmaf(tt, ca, y0);
        float fx = floorf(x), fy = floorf(y);
        float wx = x - fx, wy = y - fy;
        int c0 = (int)fx, r0 = (int)fy;
        float ux = (((unsigned)c0 < 256u) ? (1.0f - wx) : 0.0f) +
                   (((unsigned)(c0 + 1) < 256u) ? wx : 0.0f);
        float uy = (((unsigned)r0 < 256u) ? (1.0f - wy) : 0.0f) +
                   (((unsigned)(r0 + 1) < 256u) ? wy : 0.0f);
        if (t <= e2b) acc += ux * uy;
    }
    acc += __shfl_down(acc, 8, 16);
    acc += __shfl_down(acc, 4, 16);
    acc += __shfl_down(acc, 2, 16);
    acc += __shfl_down(acc, 1, 16);
    if (slane == 0) minv[ray] = fmaxf(acc + (float)count, DEN_EPS);
}

// ---------------- forward projection: 4 rays/wave, 16 lanes each ---------
// Exact-cover grid; chunk loop unrolled x2 with dual accumulators.
// MODE 1: diffs[ray] = (sino - FP) / Minv
// MODE 2: out[blockIdx.x] = block partial of sum((FP - sino)^2)
template <int MODE>
__global__ __launch_bounds__(256)
void fp_kernel(const float* __restrict__ Qn,
               const float* __restrict__ Qt,
               const float* __restrict__ sino,
               const float* __restrict__ minv,
               float* __restrict__ out,
               const float* __restrict__ cosA,
               const float* __restrict__ sinA,
               int angleStart, int angleStride, int nRays) {
    const int wid = threadIdx.x >> 6, lane = threadIdx.x & 63;
    const int sub = lane >> 4, slane = lane & 15;

    int ray = (blockIdx.x * 4 + wid) * 4 + sub;
    bool valid = ray < nRays;
    int rr = valid ? ray : nRays - 1;
    int ai = rr / NUMBIN;
    int bin = rr - ai * NUMBIN;
    int angle = angleStart + ai * angleStride;
    float ca = cosA[angle], sa = sinA[angle];
    float s = (float)bin - CDET;
    float x0 = fmaf(s, ca, CPIX);             // x(tt) = x0 - tt*sa
    float y0 = fmaf(s, sa, CPIX);             // y(tt) = y0 + tt*ca
    int itlo, nc = ray_chunks16(x0, y0, ca, sa, itlo);
    if (!valid) nc = 0;

    bool useT = fabsf(ca) > fabsf(sa);        // uniform per sub-group
    const float* img = (useT ? Qt : Qn) + (QW + 1) * 2;  // elem (0,0)
    float u0 = useT ? y0 : x0, du = useT ? ca : -sa;   // fast (contiguous)
    float v0 = useT ? x0 : y0, dv = useT ? -sa : ca;   // slow (strided)

    float tt0 = (float)(itlo + slane) - TOFF;
    float u = fmaf(tt0, du, u0);
    float v = fmaf(tt0, dv, v0);
    const float du16 = du * 16.0f, dv16 = dv * 16.0f;
    const float du32 = du * 32.0f, dv32 = dv * 32.0f;

    float acc0 = 0.0f, acc1 = 0.0f;
    int ic = 0;
    for (; ic + 1 < nc; ic += 2) {
        float uA = fminf(fmaxf(u, -1.0f), 256.0f);
        float vA = fminf(fmaxf(v, -1.0f), 256.0f);
        float uB = fminf(fmaxf(u + du16, -1.0f), 256.0f);
        float vB = fminf(fmaxf(v + dv16, -1.0f), 256.0f);
        float fuA = floorf(uA), fvA = floorf(vA);
        float fuB = floorf(uB), fvB = floorf(vB);
        float wuA = uA - fuA, wvA = vA - fvA;
        float wuB = uB - fuB, wvB = vB - fvB;
        int idxA = (int)fmaf(fvA, (float)QW, fuA);
        int idxB = (int)fmaf(fvB, (float)QW, fuB);
        f4q qA = *(const f4q*)(img + idxA * 2);
        f4q qB = *(const f4q*)(img + idxB * 2);
        float topA = fmaf(wuA, qA.z - qA.x, qA.x);
        float botA = fmaf(wuA, qA.w - qA.y, qA.y);
        acc0 += fmaf(wvA, botA - topA, topA);
        float topB = fmaf(wuB, qB.z - qB.x, qB.x);
        float botB = fmaf(wuB, qB.w - qB.y, qB.y);
        acc1 += fmaf(wvB, botB - topB, topB);
        u += du32; v += dv32;
    }
    if (ic < nc) {
        float uc = fminf(fmaxf(u, -1.0f), 256.0f);
        float vc = fminf(fmaxf(v, -1.0f), 256.0f);
        float fu = floorf(uc), fv = floorf(vc);
        float wu = uc - fu, wv = vc - fv;
        int idx = (int)fmaf(fv, (float)QW, fu);
        f4q q = *(const f4q*)(img + idx * 2);
        float top = fmaf(wu, q.z - q.x, q.x);
        float bot = fmaf(wu, q.w - q.y, q.y);
        acc0 += fmaf(wv, bot - top, top);
    }
    float acc = acc0 + acc1;
    acc += __shfl_down(acc, 8, 16);
    acc += __shfl_down(acc, 4, 16);
    acc += __shfl_down(acc, 2, 16);
    acc += __shfl_down(acc, 1, 16);

    if (MODE == 1) {
        if (slane == 0 && valid)
            out[ray] = (sino[angle * NUMBIN + bin] - acc) /
                       minv[angle * NUMBIN + bin];
    } else {
        float d2 = 0.0f;
        if (slane == 0 && valid) {
            float d = acc - sino[angle * NUMBIN + bin];
            d2 = d * d;
        }
        d2 += __shfl_down(d2, 16);
        d2 += __shfl_down(d2, 32);
        __shared__ float part[4];
        if (lane == 0) part[wid] = d2;
        __syncthreads();
        if (threadIdx.x == 0)
            out[blockIdx.x] = part[0] + part[1] + part[2] + part[3];
    }
}

// ---------------- backprojection + SART update ----------------
// pixel value read from its canonical Qf cell (no separate fk buffer)
__global__ __launch_bounds__(256)
void bp_update_kernel(float* __restrict__ Qf,
                      float* __restrict__ QTf,
                      const float* __restrict__ g,      // diffs [90,367]
                      const float* __restrict__ cosA,
                      const float* __restrict__ sinA,
                      int j, int doClamp) {
    __shared__ float part[4][64];
    const int tx = threadIdx.x & 63;
    const int ty = threadIdx.x >> 6;
    int p = blockIdx.x * 64 + tx;
    int px = p & (NUMPIX - 1), py = p >> 8;
    float X = (float)px - CPIX, Y = (float)py - CPIX;
    float acc = 0.0f;
    for (int i = ty; i < NANG_SUB; i += 4) {
        int angle = j + NS * i;
        float ca = cosA[angle], sa = sinA[angle];
        float sd = fmaf(X, ca, fmaf(Y, sa, CDET));   // always in [2.7, 363.3]
        float f0 = floorf(sd);
        float w = sd - f0;
        int i0 = (int)f0;
        f2u gv = *(const f2u*)(g + i * NUMBIN + i0);
        acc += fmaf(w, gv.y - gv.x, gv.x);
    }
    part[ty][tx] = acc;
    __syncthreads();
    if (ty == 0) {
        float s = part[0][tx] + part[1][tx] + part[2][tx] + part[3][tx];
        float bp = (fabsf(s) > 1000.0f) ? 0.0f : s;
        float v = Qf[((py + 1) * QW + (px + 1)) * 2] + bp * INV_DINV;
        if (doClamp) v = fmaxf(v, EPS_F);
        // quad-image updates: pixel (py,px) lives in 2 elements per layout
        Qf[((py + 1) * QW + (px + 1)) * 2]      = v;
        Qf[(py * QW + (px + 1)) * 2 + 1]        = v;
        QTf[((px + 1) * QW + (py + 1)) * 2]     = v;
        QTf[(px * QW + (py + 1)) * 2 + 1]       = v;
    }
}

// ---------------- select (fused residual reduce over 8258 partials) ------
__global__ __launch_bounds__(256)
void select_kernel(float* __restrict__ fcur,
                   float* __restrict__ Qf, float* __restrict__ QTf,
                   const float* __restrict__ part, int last) {
    __shared__ float buf[4];
    const int tid = threadIdx.x;
    float a = 0.0f;
    for (int idx = tid; idx < RES_BLOCKS; idx += 256) a += part[idx];
    #pragma unroll
    for (int off = 32; off; off >>= 1) a += __shfl_down(a, off);
    if ((tid & 63) == 0) buf[tid >> 6] = a;
    __syncthreads();
    float tot = buf[0] + buf[1] + buf[2] + buf[3];
    bool upd = (tot > RES2_THRESH);     // res = sqrt(res2) > 0.01
    int p = blockIdx.x * 256 + tid;
    int px = p & (NUMPIX - 1), py = p >> 8;
    float v = upd ? Qf[((py + 1) * QW + (px + 1)) * 2] : fcur[p];
    fcur[p] = v;
    if (!last) {   // dead writes after the final iteration
        Qf[((py + 1) * QW + (px + 1)) * 2]      = v;
        Qf[(py * QW + (px + 1)) * 2 + 1]        = v;
        QTf[((px + 1) * QW + (py + 1)) * 2]     = v;
        QTf[(px * QW + (py + 1)) * 2 + 1]       = v;
    }
}

extern "C" void kernel_launch(void* const* d_in, const int* in_sizes, int n_in,
                              void* d_out, int out_size, void* d_ws, size_t ws_size,
                              hipStream_t stream) {
    const float* f0 = (const float*)d_in[0];     // [256,256]
    const float* sino = (const float*)d_in[1];   // [360,367]
    float* fcur = (float*)d_out;                 // [256,256] output "f"
    float* ws = (float*)d_ws;

    float* cosA = ws + OFF_COS;
    float* sinA = ws + OFF_SIN;
    float* minv = ws + OFF_MINV;   // [360,367] indexed by global angle
    float* Qf   = ws + OFF_Q;      // quad image (normal) — canonical fk store
    float* QTf  = ws + OFF_QT;     // quad image (transposed)
    float* diff = ws + OFF_DIFF;   // [90,367]; reused as residual partials

    // init + Minv in one dispatch (Minv computes its own per-ray trig)
    init_minv_kernel<<<RES_BLOCKS, 256, 0, stream>>>(
        cosA, sinA, Qf, QTf, fcur, minv, f0);

    for (int iter = 0; iter < 2; iter++) {
        for (int j = 0; j < NS; j++) {
            fp_kernel<1><<<SUB_BLOCKS, 256, 0, stream>>>(
                Qf, QTf, sino, minv, diff, cosA, sinA, j, NS, NRAYS_SUB);
            bp_update_kernel<<<NPIX2 / 64, 256, 0, stream>>>(
                Qf, QTf, diff, cosA, sinA, j, (j == NS - 1) ? 1 : 0);
        }
        // residual: per-block partials into diff (idle here), then fused
        // reduce inside select_kernel
        fp_kernel<2><<<RES_BLOCKS, 256, 0, stream>>>(
            Qf, QTf, sino, nullptr, diff, cosA, sinA, 0, 1, NRAYS_ALL);
        select_kernel<<<NPIX2 / 256, 256, 0, stream>>>(
            fcur, Qf, QTf, diff, iter == 1);
    }
}